// Round 13
// baseline (647.483 us; speedup 1.0000x reference)
//
#include <hip/hip_runtime.h>
#include <math.h>

#define N_   1024
#define K_   8
#define OTL  3
#define SKL  3
#define GWBL 2
#define INVB 10.0f      /* 1/PROX_BETA */
#define EPSV 1e-16f
#define INVN (1.0f / 1024.0f)   /* exact: pm = probs = 1/N */
#define NN   ((size_t)N_ * N_)
#define KN   (K_ * N_)

typedef __attribute__((ext_vector_type(8))) short short8;
typedef __attribute__((ext_vector_type(4))) float f32x4;
typedef unsigned short bfu;

__device__ __forceinline__ float b2f(bfu u) {
    unsigned x = ((unsigned)u) << 16;
    return __builtin_bit_cast(float, x);
}
__device__ __forceinline__ bfu f2b(float f) {
    unsigned u = __builtin_bit_cast(unsigned, f);
    unsigned r = u + 0x7fffu + ((u >> 16) & 1u);   // RNE (finite values only)
    return (bfu)(r >> 16);
}

/* ============ bf16 MFMA GEMM: C[m][n] = sum_k A[m][k]*B[n][k] ============
   128x128 tile, BK=64 (two 32-wide sub-tiles, 32KB LDS), 256 thr = 4 waves,
   mfma 16x16x32, 32 MFMA per k-step, 16 k-steps.
   XCD affinity: z = blockIdx.x.
   EPI 0: store C bf16; if rs: block (y0,z0) zeroes rs/rs1/rs2 [z*N..]
   EPI 1: store C bf16 * wts[z]  (barycenter partials, bf16)
   EPI 2: prox in-place + atomic row-sums of new T into rs                  */
template<int EPI>
__global__ __launch_bounds__(256, 2)
void bgemm_k(const bfu* __restrict__ A, const bfu* __restrict__ B,
             void* __restrict__ Cp, size_t sA, size_t sB, size_t sC,
             const float* __restrict__ rv, const float* __restrict__ cv,
             const float* __restrict__ wts, float* __restrict__ rs) {
    __shared__ bfu As[2][128 * 32];
    __shared__ bfu Bs[2][128 * 32];

    const int z  = blockIdx.x;               // XCD-affine batch slice
    const int bm = blockIdx.y * 128, bn = blockIdx.z * 128;
    const int tid = threadIdx.x;
    const int lane = tid & 63, wv = tid >> 6;
    const int wr = wv >> 1, wc = wv & 1;

    if (EPI == 0) {   // zero the chain's three row-sum buffers for slice z
        if (rs && blockIdx.y == 0 && blockIdx.z == 0) {
            const float4 zf = {0.f, 0.f, 0.f, 0.f};
            #pragma unroll
            for (int b = 0; b < 3; ++b)
                *(float4*)&rs[b * KN + z * N_ + tid * 4] = zf;
        }
    }

    const bfu* Az = A + (size_t)z * sA;
    const bfu* Bz = B + (size_t)z * sB;

    const int sr = tid >> 2;          // staging row (0..63 per half)
    const int sk = (tid & 3) * 8;     // staging k-offset (elems)
    const int fr = lane & 15;
    const int ks = (lane >> 4) * 8;

    f32x4 acc[4][4];
    #pragma unroll
    for (int i = 0; i < 4; i++)
        #pragma unroll
        for (int j = 0; j < 4; j++) acc[i][j] = (f32x4)0.f;

    for (int k0 = 0; k0 < N_; k0 += 64) {
        __syncthreads();
        #pragma unroll
        for (int sg = 0; sg < 2; ++sg) {
            #pragma unroll
            for (int h = 0; h < 2; ++h) {
                const int row = sr + h * 64;
                const bfu* ga = Az + (size_t)(bm + row) * N_ + k0 + sg * 32 + sk;
                const bfu* gb = Bz + (size_t)(bn + row) * N_ + k0 + sg * 32 + sk;
                __builtin_amdgcn_global_load_lds(
                    (const __attribute__((address_space(1))) unsigned int*)ga,
                    (__attribute__((address_space(3))) unsigned int*)&As[sg][row * 32 + sk],
                    16, 0, 0);
                __builtin_amdgcn_global_load_lds(
                    (const __attribute__((address_space(1))) unsigned int*)gb,
                    (__attribute__((address_space(3))) unsigned int*)&Bs[sg][row * 32 + sk],
                    16, 0, 0);
            }
        }
        __syncthreads();

        #pragma unroll
        for (int sg = 0; sg < 2; ++sg) {
            short8 af[4], bf[4];
            #pragma unroll
            for (int mi = 0; mi < 4; ++mi)
                af[mi] = *(const short8*)&As[sg][(wr * 64 + mi * 16 + fr) * 32 + ks];
            #pragma unroll
            for (int ni = 0; ni < 4; ++ni)
                bf[ni] = *(const short8*)&Bs[sg][(wc * 64 + ni * 16 + fr) * 32 + ks];
            #pragma unroll
            for (int mi = 0; mi < 4; ++mi)
                #pragma unroll
                for (int ni = 0; ni < 4; ++ni)
                    acc[mi][ni] = __builtin_amdgcn_mfma_f32_16x16x32_bf16(
                        af[mi], bf[ni], acc[mi][ni], 0, 0, 0);
        }
    }

    const int r0 = bm + wr * 64, c0 = bn + wc * 64;
    const int rq = (lane >> 4) * 4;   // C/D: col=lane&15, row=(lane>>4)*4+q

    if (EPI == 1) {
        bfu* Cz = (bfu*)Cp + (size_t)z * sC;
        const float w = wts[z];
        #pragma unroll
        for (int mi = 0; mi < 4; ++mi)
            #pragma unroll
            for (int ni = 0; ni < 4; ++ni)
                #pragma unroll
                for (int q = 0; q < 4; ++q)
                    Cz[(size_t)(r0 + mi * 16 + rq + q) * N_ + c0 + ni * 16 + fr]
                        = f2b(w * acc[mi][ni][q]);
    } else if (EPI == 0) {
        bfu* Cz = (bfu*)Cp + (size_t)z * sC;
        #pragma unroll
        for (int mi = 0; mi < 4; ++mi)
            #pragma unroll
            for (int ni = 0; ni < 4; ++ni)
                #pragma unroll
                for (int q = 0; q < 4; ++q)
                    Cz[(size_t)(r0 + mi * 16 + rq + q) * N_ + c0 + ni * 16 + fr]
                        = f2b(acc[mi][ni][q]);
    } else {  // EPI == 2: prox in place on Tt + row-sum atomics
        bfu* Cz = (bfu*)Cp + (size_t)z * sC;
        const float* rvz = rv + z * N_;
        float rsum[4][4];
        #pragma unroll
        for (int mi = 0; mi < 4; ++mi)
            #pragma unroll
            for (int q = 0; q < 4; ++q) rsum[mi][q] = 0.f;
        #pragma unroll
        for (int mi = 0; mi < 4; ++mi)
            #pragma unroll
            for (int ni = 0; ni < 4; ++ni)
                #pragma unroll
                for (int q = 0; q < 4; ++q) {
                    const int row = r0 + mi * 16 + rq + q;
                    const int col = c0 + ni * 16 + fr;
                    const float cost = rvz[col] + cv[row] - 2.f * acc[mi][ni][q];
                    const float t = b2f(Cz[(size_t)row * N_ + col]);
                    const bfu tn = f2b(expf(-cost * INVB) * t);
                    Cz[(size_t)row * N_ + col] = tn;
                    rsum[mi][q] += b2f(tn);
                }
        #pragma unroll
        for (int mi = 0; mi < 4; ++mi)
            #pragma unroll
            for (int q = 0; q < 4; ++q) {
                float v = rsum[mi][q];
                v += __shfl_xor(v, 1);
                v += __shfl_xor(v, 2);
                v += __shfl_xor(v, 4);
                v += __shfl_xor(v, 8);
                if (fr == 0)
                    atomicAdd(&rs[z * N_ + r0 + mi * 16 + rq + q], v);
            }
    }
}

/* ============ 64x64-tile GEMM (final fgwd, full-chip occupancy) ============
   BK=128 (four 32-wide sub-tiles, 32KB LDS): 8 k-steps, 16 MFMA/step.
   Grid (16 n-tiles [XCD], 16 m-tiles).
   EPI 0: store bf16; block(0,0) zeroes rs/rs1/rs2 and/or dout
   EPI 2: prox in-place on Tt (rv[col]+cv[row]) + rs row-sum atomics
   EPI 3: distance: atomicAdd(dout, sum (rv[col]+cv[row]-2acc)*Tt[row][col]) */
template<int EPI>
__global__ __launch_bounds__(256, 2)
void gemm64_k(const bfu* __restrict__ A, const bfu* __restrict__ B,
              void* __restrict__ Cp,
              const float* __restrict__ rv, const float* __restrict__ cv,
              float* __restrict__ rs, float* __restrict__ dout) {
    __shared__ bfu As[4][64 * 32];
    __shared__ bfu Bs[4][64 * 32];
    const int bn = blockIdx.x * 64;     // XCD-affine (flat%8 = bx%8)
    const int bm = blockIdx.y * 64;
    const int tid = threadIdx.x;
    const int lane = tid & 63, wv = tid >> 6;
    const int wr = wv >> 1, wc = wv & 1;
    const int sr = tid >> 2, sk = (tid & 3) * 8;
    const int fr = lane & 15, ks = (lane >> 4) * 8;

    if (EPI == 0) {
        if (blockIdx.x == 0 && blockIdx.y == 0) {
            if (rs) {
                const float4 zf = {0.f, 0.f, 0.f, 0.f};
                #pragma unroll
                for (int b = 0; b < 3; ++b)
                    *(float4*)&rs[b * KN + tid * 4] = zf;
            }
            if (dout && tid == 0) *dout = 0.f;
        }
    }

    f32x4 acc[2][2];
    #pragma unroll
    for (int i = 0; i < 2; i++)
        #pragma unroll
        for (int j = 0; j < 2; j++) acc[i][j] = (f32x4)0.f;

    for (int k0 = 0; k0 < N_; k0 += 128) {
        __syncthreads();
        #pragma unroll
        for (int sg = 0; sg < 4; ++sg) {
            __builtin_amdgcn_global_load_lds(
                (const __attribute__((address_space(1))) unsigned int*)
                    (A + (size_t)(bm + sr) * N_ + k0 + sg * 32 + sk),
                (__attribute__((address_space(3))) unsigned int*)&As[sg][sr * 32 + sk],
                16, 0, 0);
            __builtin_amdgcn_global_load_lds(
                (const __attribute__((address_space(1))) unsigned int*)
                    (B + (size_t)(bn + sr) * N_ + k0 + sg * 32 + sk),
                (__attribute__((address_space(3))) unsigned int*)&Bs[sg][sr * 32 + sk],
                16, 0, 0);
        }
        __syncthreads();
        #pragma unroll
        for (int sg = 0; sg < 4; ++sg) {
            short8 af[2], bf[2];
            #pragma unroll
            for (int mi = 0; mi < 2; ++mi)
                af[mi] = *(const short8*)&As[sg][(wr * 32 + mi * 16 + fr) * 32 + ks];
            #pragma unroll
            for (int ni = 0; ni < 2; ++ni)
                bf[ni] = *(const short8*)&Bs[sg][(wc * 32 + ni * 16 + fr) * 32 + ks];
            #pragma unroll
            for (int mi = 0; mi < 2; ++mi)
                #pragma unroll
                for (int ni = 0; ni < 2; ++ni)
                    acc[mi][ni] = __builtin_amdgcn_mfma_f32_16x16x32_bf16(
                        af[mi], bf[ni], acc[mi][ni], 0, 0, 0);
        }
    }

    const int r0 = bm + wr * 32, c0 = bn + wc * 32;
    const int rq = (lane >> 4) * 4;

    if (EPI == 0) {
        bfu* C = (bfu*)Cp;
        #pragma unroll
        for (int mi = 0; mi < 2; ++mi)
            #pragma unroll
            for (int ni = 0; ni < 2; ++ni)
                #pragma unroll
                for (int q = 0; q < 4; ++q)
                    C[(size_t)(r0 + mi * 16 + rq + q) * N_ + c0 + ni * 16 + fr]
                        = f2b(acc[mi][ni][q]);
    } else if (EPI == 2) {
        bfu* C = (bfu*)Cp;
        float rsum[2][4];
        #pragma unroll
        for (int mi = 0; mi < 2; ++mi)
            #pragma unroll
            for (int q = 0; q < 4; ++q) rsum[mi][q] = 0.f;
        #pragma unroll
        for (int mi = 0; mi < 2; ++mi)
            #pragma unroll
            for (int ni = 0; ni < 2; ++ni)
                #pragma unroll
                for (int q = 0; q < 4; ++q) {
                    const int row = r0 + mi * 16 + rq + q;
                    const int col = c0 + ni * 16 + fr;
                    const float cost = rv[col] + cv[row] - 2.f * acc[mi][ni][q];
                    const float t = b2f(C[(size_t)row * N_ + col]);
                    const bfu tn = f2b(expf(-cost * INVB) * t);
                    C[(size_t)row * N_ + col] = tn;
                    rsum[mi][q] += b2f(tn);
                }
        #pragma unroll
        for (int mi = 0; mi < 2; ++mi)
            #pragma unroll
            for (int q = 0; q < 4; ++q) {
                float v = rsum[mi][q];
                v += __shfl_xor(v, 1);
                v += __shfl_xor(v, 2);
                v += __shfl_xor(v, 4);
                v += __shfl_xor(v, 8);
                if (fr == 0)
                    atomicAdd(&rs[r0 + mi * 16 + rq + q], v);
            }
    } else {  // EPI == 3: distance reduce
        const bfu* C = (const bfu*)Cp;
        float bs = 0.f;
        #pragma unroll
        for (int mi = 0; mi < 2; ++mi)
            #pragma unroll
            for (int ni = 0; ni < 2; ++ni)
                #pragma unroll
                for (int q = 0; q < 4; ++q) {
                    const int row = r0 + mi * 16 + rq + q;
                    const int col = c0 + ni * 16 + fr;
                    bs += (rv[col] + cv[row] - 2.f * acc[mi][ni][q]) *
                          b2f(C[(size_t)row * N_ + col]);
                }
        #pragma unroll
        for (int off = 32; off; off >>= 1) bs += __shfl_down(bs, off);
        __shared__ float wred[4];
        if (lane == 0) wred[wv] = bs;
        __syncthreads();
        if (tid == 0) atomicAdd(dout, wred[0] + wred[1] + wred[2] + wred[3]);
    }
}

/* ============ rank-1 first OT step (it=0): prox + first b + rs zeroing ==== */
__global__ __launch_bounds__(256)
void prox1_k(bfu* __restrict__ Tt, const float* __restrict__ c2,
             const float* __restrict__ u, const float* __restrict__ d2,
             const float* __restrict__ w, const float* __restrict__ ps,
             const float* __restrict__ pb, float* __restrict__ bv,
             float* __restrict__ rs1, int zs, int nb) {
    const int b = blockIdx.x;
    const int z  = (nb == 8) ? (b & 7) : 0;      // XCD-affine
    const int rp = (nb == 8) ? (b >> 3) : b;
    const int tid = threadIdx.x;

    if (rp < 2) {   // zero rs1 (rp==0) / rs2 (rp==1) for slice z
        const float4 zf = {0.f, 0.f, 0.f, 0.f};
        *(float4*)&rs1[rp * KN + z * N_ + tid * 4] = zf;
    }

    const int half = tid >> 7;
    const int j = rp * 2 + half;
    const int i0 = (tid & 127) * 8;
    const float d2j = d2[j], wj = w[j], pbj = pb[j];
    const float* c2z = c2 + z * zs + i0;
    const float* uz  = u  + z * zs + i0;
    const float* psz = ps + z * zs + i0;
    bfu o[8];
    float s = 0.f;
    #pragma unroll
    for (int t = 0; t < 8; ++t) {
        const float cost = c2z[t] + d2j - 2.f * uz[t] * wj;
        o[t] = f2b(expf(-cost * INVB) * psz[t] * pbj);
        s += b2f(o[t]);
    }
    *(short8*)&Tt[((size_t)z << 20) + ((size_t)j << 10) + i0] = *(short8*)o;
    #pragma unroll
    for (int off = 32; off; off >>= 1) s += __shfl_down(s, off);
    __shared__ float red[4];
    if ((tid & 63) == 0) red[tid >> 6] = s;
    __syncthreads();
    if ((tid & 127) == 0)
        bv[z * N_ + j] = pbj / ((red[half * 2] + red[half * 2 + 1]) * INVN + EPSV);
}

/* ============ merged reduce8 + prox (row-per-block, 2 rows each) ============ */
template<int NB>
__global__ __launch_bounds__(256)
void redprox_k(const bfu* __restrict__ part, bfu* __restrict__ Gbt,
               float* __restrict__ d2out, float* __restrict__ wout,
               float* __restrict__ out1,
               const float* __restrict__ c2, const float* __restrict__ u,
               bfu* __restrict__ Tt, float* __restrict__ bv,
               float* __restrict__ rs12) {
    const int tid = threadIdx.x;
    if (blockIdx.x < 16) {   // zero rs1|rs2 (2*KN floats across 16 blocks)
        const float4 zf = {0.f, 0.f, 0.f, 0.f};
        *(float4*)&rs12[blockIdx.x * 1024 + tid * 4] = zf;
    }
    __shared__ float red[8];
    __shared__ float bc[2];
    #pragma unroll
    for (int rep = 0; rep < 2; ++rep) {
        const int row = blockIdx.x + rep * 512;
        const size_t idx = (size_t)row * N_ + tid * 4;
        float4 s = {0.f, 0.f, 0.f, 0.f};
        #pragma unroll
        for (int sl = 0; sl < K_; ++sl) {
            bfu p[4];
            *(ulong1*)p = *(const ulong1*)&part[(size_t)sl * NN + idx];
            s.x += b2f(p[0]); s.y += b2f(p[1]);
            s.z += b2f(p[2]); s.w += b2f(p[3]);
        }
        const float sc = 1048576.f;   // N^2 (pm uniform)
        s.x *= sc; s.y *= sc; s.z *= sc; s.w *= sc;
        bfu o[4];
        o[0] = f2b(s.x); o[1] = f2b(s.y); o[2] = f2b(s.z); o[3] = f2b(s.w);
        *(ulong1*)&Gbt[idx] = *(ulong1*)o;
        if (out1) {   // out+1 is only 4B-aligned: scalar stores
            out1[idx + 0] = s.x; out1[idx + 1] = s.y;
            out1[idx + 2] = s.z; out1[idx + 3] = s.w;
        }
        float r2 = s.x * s.x + s.y * s.y + s.z * s.z + s.w * s.w;
        float r1 = s.x + s.y + s.z + s.w;
        #pragma unroll
        for (int off = 32; off; off >>= 1) {
            r2 += __shfl_down(r2, off);
            r1 += __shfl_down(r1, off);
        }
        if ((tid & 63) == 0) {
            red[(tid >> 6) * 2]     = r2;
            red[(tid >> 6) * 2 + 1] = r1;
        }
        __syncthreads();
        if (tid == 0) {
            const float d2j = (red[0] + red[2] + red[4] + red[6]) * INVN;
            const float wj  = (red[1] + red[3] + red[5] + red[7]) * INVN;
            d2out[row] = d2j; wout[row] = wj;
            bc[0] = d2j; bc[1] = wj;
        }
        __syncthreads();
        const float d2j = bc[0], wj = bc[1];
        const float sc2 = INVN * INVN;   // ps * pb (both uniform)
        #pragma unroll
        for (int z = 0; z < NB; ++z) {
            const float4 cv4 = *(const float4*)(c2 + z * N_ + tid * 4);
            const float4 uv4 = *(const float4*)(u  + z * N_ + tid * 4);
            bfu t[4];
            t[0] = f2b(expf(-(cv4.x + d2j - 2.f * uv4.x * wj) * INVB) * sc2);
            t[1] = f2b(expf(-(cv4.y + d2j - 2.f * uv4.y * wj) * INVB) * sc2);
            t[2] = f2b(expf(-(cv4.z + d2j - 2.f * uv4.z * wj) * INVB) * sc2);
            t[3] = f2b(expf(-(cv4.w + d2j - 2.f * uv4.w * wj) * INVB) * sc2);
            *(ulong1*)&Tt[(size_t)z * NN + idx] = *(ulong1*)t;
            float rsum = b2f(t[0]) + b2f(t[1]) + b2f(t[2]) + b2f(t[3]);
            #pragma unroll
            for (int off = 32; off; off >>= 1) rsum += __shfl_down(rsum, off);
            if ((tid & 63) == 0) red[tid >> 6] = rsum;
            __syncthreads();
            if (tid == 0)
                bv[z * N_ + row] = INVN /
                    ((red[0] + red[1] + red[2] + red[3]) * INVN + EPSV);
            __syncthreads();
        }
    }
}

/* ============ Sinkhorn column pass (register-resident, z -> XCD affine) ====
   NB=8: 512 blocks, 16-col stripe, 2 rows/thread. NB=1: 128 blocks, 8-col
   stripe, 1 row/thread. Each thread holds its short8 row-segment(s) in
   registers across all phases (no re-read). Wave shfl tree -> per-wave
   chunk sums -> tiny LDS -> avs.
   BSRC: 0 bvin | 1 raw row-sums*INVN | 2 a-weighted row-sums.
   TUPD=0: emit rs'[j] += dot(seg, avs) (vc-combined, 1 atomic/row)
   TUPD=1: T[j][c] = seg*avs[c]*bvs[j] written back from registers.         */
template<int NB, int BSRC, int TUPD>
__global__ __launch_bounds__(1024)
void sinka_k(bfu* __restrict__ Tt, const float* __restrict__ bvin,
             const float* __restrict__ rsin, const float* __restrict__ ps,
             int pstr, float* __restrict__ rsnext) {
    constexpr int CPB  = (NB == 8) ? 16 : 8;   // cols per block
    constexpr int RPT  = (NB == 8) ? 2 : 1;    // rows per thread
    constexpr int FIRST = (NB == 8) ? 2 : 1;   // first shfl offset
    int z, cb;
    if (NB == 8) { z = blockIdx.x & 7; cb = blockIdx.x >> 3; }   // 512 blocks
    else         { z = 0;              cb = blockIdx.x; }        // 128 blocks
    const int tid = threadIdx.x;
    const int vc = (NB == 8) ? (tid & 1) : 0;
    const int rg = (NB == 8) ? (tid >> 1) : tid;
    const int c0 = cb * CPB + vc * 8;
    const int zN = z * N_;
    bfu* Tz = Tt + (size_t)z * NN;

    __shared__ float bvs[1024];
    __shared__ float red[16][CPB];
    __shared__ float avs[CPB];
    if (BSRC == 0)      bvs[tid] = bvin[zN + tid];
    else if (BSRC == 1) bvs[tid] = INVN / (rsin[zN + tid] * INVN + EPSV);
    else                bvs[tid] = INVN / (rsin[zN + tid] + EPSV);
    __syncthreads();

    // load row segments into registers; accumulate per-col partials
    bfu tr[RPT][8];
    float rowb[RPT];
    float sc[8];
    #pragma unroll
    for (int q = 0; q < 8; ++q) sc[q] = 0.f;
    #pragma unroll
    for (int r = 0; r < RPT; ++r) {
        const int j = rg * RPT + r;
        rowb[r] = bvs[j];
        *(short8*)tr[r] = *(const short8*)&Tz[(size_t)j * N_ + c0];
        #pragma unroll
        for (int q = 0; q < 8; ++q) sc[q] += b2f(tr[r][q]) * rowb[r];
    }
    // wave reduce over row-groups (keeps vc parity for NB=8)
    #pragma unroll
    for (int off = FIRST; off < 64; off <<= 1)
        #pragma unroll
        for (int q = 0; q < 8; ++q) sc[q] += __shfl_down(sc[q], off);
    const int wv = tid >> 6, lane = tid & 63;
    if (lane < FIRST) {
        const int cbase = (NB == 8) ? lane * 8 : 0;
        #pragma unroll
        for (int q = 0; q < 8; ++q) red[wv][cbase + q] = sc[q];
    }
    __syncthreads();
    if (tid < CPB) {
        float s = 0.f;
        #pragma unroll
        for (int w = 0; w < 16; ++w) s += red[w][tid];
        avs[tid] = ps[z * pstr + cb * CPB + tid] / (s + EPSV);
    }
    __syncthreads();

    if (TUPD) {
        #pragma unroll
        for (int r = 0; r < RPT; ++r) {
            const int j = rg * RPT + r;
            bfu o[8];
            #pragma unroll
            for (int q = 0; q < 8; ++q)
                o[q] = f2b(b2f(tr[r][q]) * avs[vc * 8 + q] * rowb[r]);
            *(short8*)&Tz[(size_t)j * N_ + c0] = *(short8*)o;
        }
    } else {
        float v[RPT];
        #pragma unroll
        for (int r = 0; r < RPT; ++r) {
            v[r] = 0.f;
            #pragma unroll
            for (int q = 0; q < 8; ++q)
                v[r] += b2f(tr[r][q]) * avs[vc * 8 + q];
        }
        if (NB == 8) {
            // lanes 2k / 2k+1 share rows: combine, vc==0 emits
            #pragma unroll
            for (int r = 0; r < RPT; ++r) v[r] += __shfl_xor(v[r], 1);
            if (vc == 0) {
                #pragma unroll
                for (int r = 0; r < RPT; ++r)
                    atomicAdd(&rsnext[zN + rg * RPT + r], v[r]);
            }
        } else {
            atomicAdd(&rsnext[zN + tid], v[0]);
        }
    }
}

/* ============ merged prep: atoms (z<8, sigmoid) + Gm (z==8) ============ */
__global__ void prep_k(const float* __restrict__ atoms, const float* __restrict__ Gm,
                       bfu* __restrict__ Gkt, bfu* __restrict__ Gmt,
                       float* __restrict__ Gk2ps, float* __restrict__ Gku,
                       float* __restrict__ Gm2pm, float* __restrict__ Gmu) {
    const int z = blockIdx.y;
    const int sig = (z < 8);
    const float* X = sig ? atoms + (size_t)z * NN : Gm;
    bfu*  Y  = sig ? Gkt + (size_t)z * NN : Gmt;
    float* y2 = sig ? Gk2ps + z * N_ : Gm2pm;
    float* y1 = sig ? Gku + z * N_ : Gmu;
    const int wv = threadIdx.x >> 6, lane = threadIdx.x & 63;
    const int r = blockIdx.x * 4 + wv;
    const float* Xr = X + (size_t)r * N_;
    bfu* Yr = Y + (size_t)r * N_;
    float s2 = 0.f, s1 = 0.f;
    for (int c = lane * 4; c < N_; c += 256) {
        float4 v = *(const float4*)(Xr + c);
        if (sig) {
            v.x = 1.f / (1.f + expf(-v.x));
            v.y = 1.f / (1.f + expf(-v.y));
            v.z = 1.f / (1.f + expf(-v.z));
            v.w = 1.f / (1.f + expf(-v.w));
        }
        bfu o[4];
        o[0] = f2b(v.x); o[1] = f2b(v.y); o[2] = f2b(v.z); o[3] = f2b(v.w);
        *(ulong1*)&Yr[c] = *(ulong1*)o;
        s2 += v.x * v.x + v.y * v.y + v.z * v.z + v.w * v.w;
        s1 += v.x + v.y + v.z + v.w;
    }
    #pragma unroll
    for (int off = 32; off; off >>= 1) {
        s2 += __shfl_down(s2, off);
        s1 += __shfl_down(s1, off);
    }
    if (lane == 0) {
        y2[r] = s2 * INVN;
        y1[r] = s1 * INVN;
    }
}

/* ============ host sequence ============ */

// Full Sinkhorn (3 iterations) in 3 dispatches.
template<int NB, int BSRC1>
static inline void sink_tail(bfu* Tt, const float* ps, int pstr,
                             float* bvec, float* rs, hipStream_t stream) {
    const dim3 ga((NB == 8) ? 512 : 128);
    float* rs1 = rs + KN;
    float* rs2 = rs + 2 * KN;
    sinka_k<NB, BSRC1, 0><<<ga, dim3(1024), 0, stream>>>(Tt, bvec, rs, ps, pstr, rs1);
    sinka_k<NB, 2, 0><<<ga, dim3(1024), 0, stream>>>(Tt, nullptr, rs1, ps, pstr, rs2);
    sinka_k<NB, 2, 1><<<ga, dim3(1024), 0, stream>>>(Tt, nullptr, rs2, ps, pstr, nullptr);
}

extern "C" void kernel_launch(void* const* d_in, const int* in_sizes, int n_in,
                              void* d_out, int out_size, void* d_ws, size_t ws_size,
                              hipStream_t stream) {
    const float* Gm    = (const float*)d_in[0];
    const float* pm    = (const float*)d_in[1];
    const float* atoms = (const float*)d_in[2];
    const float* probs = (const float*)d_in[3];
    const float* wts   = (const float*)d_in[4];
    float* out = (float*)d_out;                  // [0]=d_fgw, [1..]=G_bary (fp32)

    char* base = (char*)d_ws;
    bfu*   Gkt  = (bfu*)base;                    base += K_ * NN * 2;
    bfu*   Tt   = (bfu*)base;                    base += K_ * NN * 2;
    bfu*   M    = (bfu*)base;                    base += K_ * NN * 2;
    bfu*   part = (bfu*)base;                    base += K_ * NN * 2;
    bfu*   Gbt  = (bfu*)base;                    base += NN * 2;
    bfu*   Gmt  = (bfu*)base;                    base += NN * 2;
    float* Gk2ps = (float*)base;                 base += KN * 4;
    float* Gku   = (float*)base;                 base += KN * 4;
    float* Gm2pm = (float*)base;                 base += N_ * 4;
    float* Gmu   = (float*)base;                 base += N_ * 4;
    float* Gb2pb = (float*)base;                 base += N_ * 4;
    float* Gbw   = (float*)base;                 base += N_ * 4;
    float* bvec  = (float*)base;                 base += KN * 4;
    float* rs    = (float*)base;                 base += 3 * KN * 4;  // rs|rs1|rs2

    const dim3 blk(256);
    const dim3 g8(8, 8, 8);      // (z, m-tile, n-tile): z -> XCD
    const dim3 g64(16, 16);      // 64^2 tiles: n-tile -> XCD

    // merged setup: atoms sigmoid cast + moments (z<8), Gm cast + moments (z=8)
    prep_k<<<dim3(256, 9), blk, 0, stream>>>(atoms, Gm, Gkt, Gmt,
                                             Gk2ps, Gku, Gm2pm, Gmu);

    for (int it = 0; it < GWBL; ++it) {
        // iteration 0: barycenter == Gm; iteration 1: Gb written by redprox
        const bfu*   GbtU = it ? Gbt : Gmt;
        const float* d2U  = it ? Gb2pb : Gm2pm;

        if (it == 0)   // rank-1 prox vs Gm (+ first-b + rs1/rs2 zeroing)
            prox1_k<<<512 * K_, blk, 0, stream>>>(Tt, Gk2ps, Gku, Gm2pm, Gmu,
                                                  probs, pm, bvec, rs + KN, N_, K_);
        // else: redprox_k<8> at end of previous iter already wrote Tt/bvec/rs
        sink_tail<K_, 0>(Tt, probs, N_, bvec, rs, stream);
        for (int ot = 1; ot < OTL; ++ot) {
            // M[i][n] = sum_k Gk[i][k]*Tt[n][k]  (= Gs @ T); zero rs buffers
            bgemm_k<0><<<g8, blk, 0, stream>>>(Gkt, Tt, M, NN, NN, NN,
                nullptr, nullptr, nullptr, rs);
            // prox in place + row-sum atomics -> rs
            bgemm_k<2><<<g8, blk, 0, stream>>>(GbtU, M, Tt, 0, NN, NN,
                Gk2ps, d2U, nullptr, rs);
            sink_tail<K_, 1>(Tt, probs, N_, bvec, rs, stream);
        }
        // GTt[j][i'] = sum_k Tt[j][k]*Gk[i'][k]   (= (Gk @ T)^T)
        bgemm_k<0><<<g8, blk, 0, stream>>>(Tt, Gkt, M, NN, NN, NN,
            nullptr, nullptr, nullptr, nullptr);
        // part[z][i][j] = bf16( w_z * sum_n Tt[z][i][n]*GTt[z][j][n] )
        bgemm_k<1><<<g8, blk, 0, stream>>>(Tt, M, part, NN, NN, NN,
            nullptr, nullptr, wts, nullptr);
        // merged: Gb combine + moments + prox for next phase + first-b + rs zero
        if (it == 0)
            redprox_k<8><<<512, blk, 0, stream>>>(part, Gbt, Gb2pb, Gbw,
                nullptr, Gk2ps, Gku, Tt, bvec, rs + KN);
        else
            redprox_k<1><<<512, blk, 0, stream>>>(part, Gbt, Gb2pb, Gbw,
                out + 1, Gm2pm, Gmu, Tt, bvec, rs + KN);
    }

    // ---- final fgwd(Gm, pm, Gb, pm) — Tt/bvec already set by redprox<1> ----
    sink_tail<1, 0>(Tt, pm, 0, bvec, rs, stream);
    for (int ot = 1; ot < OTL; ++ot) {
        gemm64_k<0><<<g64, blk, 0, stream>>>(Gmt, Tt, M,
            nullptr, nullptr, rs, nullptr);
        gemm64_k<2><<<g64, blk, 0, stream>>>(Gbt, M, Tt,
            Gm2pm, Gb2pb, rs, nullptr);
        sink_tail<1, 1>(Tt, pm, 0, bvec, rs, stream);
    }
    // d = sum_ij (Gm2pm[i] + Gb2pb[j] - 2*(Gm T Gb^T)[i][j]) * T[i][j]
    gemm64_k<0><<<g64, blk, 0, stream>>>(Gmt, Tt, M,
        nullptr, nullptr, nullptr, out /* zero d */);
    gemm64_k<3><<<g64, blk, 0, stream>>>(Gbt, M, Tt,
        Gm2pm, Gb2pb, nullptr, out);
}

// Round 14
// 622.291 us; speedup vs baseline: 1.0405x; 1.0405x over previous
//
#include <hip/hip_runtime.h>
#include <math.h>

#define N_   1024
#define K_   8
#define OTL  3
#define SKL  3
#define GWBL 2
#define INVB 10.0f      /* 1/PROX_BETA */
#define EPSV 1e-16f
#define INVN (1.0f / 1024.0f)   /* exact: pm = probs = 1/N */
#define NN   ((size_t)N_ * N_)
#define KN   (K_ * N_)

typedef __attribute__((ext_vector_type(8))) short short8;
typedef __attribute__((ext_vector_type(4))) float f32x4;
typedef unsigned short bfu;

__device__ __forceinline__ float b2f(bfu u) {
    unsigned x = ((unsigned)u) << 16;
    return __builtin_bit_cast(float, x);
}
__device__ __forceinline__ bfu f2b(float f) {
    unsigned u = __builtin_bit_cast(unsigned, f);
    unsigned r = u + 0x7fffu + ((u >> 16) & 1u);   // RNE (finite values only)
    return (bfu)(r >> 16);
}

/* ============ bf16 MFMA GEMM: C[m][n] = sum_k A[m][k]*B[n][k] ============
   128x128 tile, BK=64 (two 32-wide sub-tiles, 32KB LDS), 256 thr = 4 waves,
   mfma 16x16x32, 32 MFMA per k-step, 16 k-steps.
   XCD affinity: z = blockIdx.x.
   EPI 0: store C bf16; if rs: block (y0,z0) zeroes rs/rs1/rs2 [z*N..]
   EPI 1: store C bf16 * wts[z]  (barycenter partials, bf16)
   EPI 2: prox in-place + atomic row-sums of new T into rs                  */
template<int EPI>
__global__ __launch_bounds__(256, 2)
void bgemm_k(const bfu* __restrict__ A, const bfu* __restrict__ B,
             void* __restrict__ Cp, size_t sA, size_t sB, size_t sC,
             const float* __restrict__ rv, const float* __restrict__ cv,
             const float* __restrict__ wts, float* __restrict__ rs) {
    __shared__ bfu As[2][128 * 32];
    __shared__ bfu Bs[2][128 * 32];

    const int z  = blockIdx.x;               // XCD-affine batch slice
    const int bm = blockIdx.y * 128, bn = blockIdx.z * 128;
    const int tid = threadIdx.x;
    const int lane = tid & 63, wv = tid >> 6;
    const int wr = wv >> 1, wc = wv & 1;

    if (EPI == 0) {   // zero the chain's three row-sum buffers for slice z
        if (rs && blockIdx.y == 0 && blockIdx.z == 0) {
            const float4 zf = {0.f, 0.f, 0.f, 0.f};
            #pragma unroll
            for (int b = 0; b < 3; ++b)
                *(float4*)&rs[b * KN + z * N_ + tid * 4] = zf;
        }
    }

    const bfu* Az = A + (size_t)z * sA;
    const bfu* Bz = B + (size_t)z * sB;

    const int sr = tid >> 2;          // staging row (0..63 per half)
    const int sk = (tid & 3) * 8;     // staging k-offset (elems)
    const int fr = lane & 15;
    const int ks = (lane >> 4) * 8;

    f32x4 acc[4][4];
    #pragma unroll
    for (int i = 0; i < 4; i++)
        #pragma unroll
        for (int j = 0; j < 4; j++) acc[i][j] = (f32x4)0.f;

    for (int k0 = 0; k0 < N_; k0 += 64) {
        __syncthreads();
        #pragma unroll
        for (int sg = 0; sg < 2; ++sg) {
            #pragma unroll
            for (int h = 0; h < 2; ++h) {
                const int row = sr + h * 64;
                const bfu* ga = Az + (size_t)(bm + row) * N_ + k0 + sg * 32 + sk;
                const bfu* gb = Bz + (size_t)(bn + row) * N_ + k0 + sg * 32 + sk;
                __builtin_amdgcn_global_load_lds(
                    (const __attribute__((address_space(1))) unsigned int*)ga,
                    (__attribute__((address_space(3))) unsigned int*)&As[sg][row * 32 + sk],
                    16, 0, 0);
                __builtin_amdgcn_global_load_lds(
                    (const __attribute__((address_space(1))) unsigned int*)gb,
                    (__attribute__((address_space(3))) unsigned int*)&Bs[sg][row * 32 + sk],
                    16, 0, 0);
            }
        }
        __syncthreads();

        #pragma unroll
        for (int sg = 0; sg < 2; ++sg) {
            short8 af[4], bf[4];
            #pragma unroll
            for (int mi = 0; mi < 4; ++mi)
                af[mi] = *(const short8*)&As[sg][(wr * 64 + mi * 16 + fr) * 32 + ks];
            #pragma unroll
            for (int ni = 0; ni < 4; ++ni)
                bf[ni] = *(const short8*)&Bs[sg][(wc * 64 + ni * 16 + fr) * 32 + ks];
            #pragma unroll
            for (int mi = 0; mi < 4; ++mi)
                #pragma unroll
                for (int ni = 0; ni < 4; ++ni)
                    acc[mi][ni] = __builtin_amdgcn_mfma_f32_16x16x32_bf16(
                        af[mi], bf[ni], acc[mi][ni], 0, 0, 0);
        }
    }

    const int r0 = bm + wr * 64, c0 = bn + wc * 64;
    const int rq = (lane >> 4) * 4;   // C/D: col=lane&15, row=(lane>>4)*4+q

    if (EPI == 1) {
        bfu* Cz = (bfu*)Cp + (size_t)z * sC;
        const float w = wts[z];
        #pragma unroll
        for (int mi = 0; mi < 4; ++mi)
            #pragma unroll
            for (int ni = 0; ni < 4; ++ni)
                #pragma unroll
                for (int q = 0; q < 4; ++q)
                    Cz[(size_t)(r0 + mi * 16 + rq + q) * N_ + c0 + ni * 16 + fr]
                        = f2b(w * acc[mi][ni][q]);
    } else if (EPI == 0) {
        bfu* Cz = (bfu*)Cp + (size_t)z * sC;
        #pragma unroll
        for (int mi = 0; mi < 4; ++mi)
            #pragma unroll
            for (int ni = 0; ni < 4; ++ni)
                #pragma unroll
                for (int q = 0; q < 4; ++q)
                    Cz[(size_t)(r0 + mi * 16 + rq + q) * N_ + c0 + ni * 16 + fr]
                        = f2b(acc[mi][ni][q]);
    } else {  // EPI == 2: prox in place on Tt + row-sum atomics
        bfu* Cz = (bfu*)Cp + (size_t)z * sC;
        const float* rvz = rv + z * N_;
        float rsum[4][4];
        #pragma unroll
        for (int mi = 0; mi < 4; ++mi)
            #pragma unroll
            for (int q = 0; q < 4; ++q) rsum[mi][q] = 0.f;
        #pragma unroll
        for (int mi = 0; mi < 4; ++mi)
            #pragma unroll
            for (int ni = 0; ni < 4; ++ni)
                #pragma unroll
                for (int q = 0; q < 4; ++q) {
                    const int row = r0 + mi * 16 + rq + q;
                    const int col = c0 + ni * 16 + fr;
                    const float cost = rvz[col] + cv[row] - 2.f * acc[mi][ni][q];
                    const float t = b2f(Cz[(size_t)row * N_ + col]);
                    const bfu tn = f2b(expf(-cost * INVB) * t);
                    Cz[(size_t)row * N_ + col] = tn;
                    rsum[mi][q] += b2f(tn);
                }
        #pragma unroll
        for (int mi = 0; mi < 4; ++mi)
            #pragma unroll
            for (int q = 0; q < 4; ++q) {
                float v = rsum[mi][q];
                v += __shfl_xor(v, 1);
                v += __shfl_xor(v, 2);
                v += __shfl_xor(v, 4);
                v += __shfl_xor(v, 8);
                if (fr == 0)
                    atomicAdd(&rs[z * N_ + r0 + mi * 16 + rq + q], v);
            }
    }
}

/* ============ 64x64-tile GEMM (final fgwd, full-chip occupancy) ============
   BK=128 (four 32-wide sub-tiles, 32KB LDS): 8 k-steps, 16 MFMA/step.
   Grid (16 n-tiles [XCD], 16 m-tiles).
   EPI 0: store bf16; block(0,0) zeroes rs/rs1/rs2 and/or dout
   EPI 2: prox in-place on Tt (rv[col]+cv[row]) + rs row-sum atomics
   EPI 3: distance: atomicAdd(dout, sum (rv[col]+cv[row]-2acc)*Tt[row][col]) */
template<int EPI>
__global__ __launch_bounds__(256, 2)
void gemm64_k(const bfu* __restrict__ A, const bfu* __restrict__ B,
              void* __restrict__ Cp,
              const float* __restrict__ rv, const float* __restrict__ cv,
              float* __restrict__ rs, float* __restrict__ dout) {
    __shared__ bfu As[4][64 * 32];
    __shared__ bfu Bs[4][64 * 32];
    const int bn = blockIdx.x * 64;     // XCD-affine (flat%8 = bx%8)
    const int bm = blockIdx.y * 64;
    const int tid = threadIdx.x;
    const int lane = tid & 63, wv = tid >> 6;
    const int wr = wv >> 1, wc = wv & 1;
    const int sr = tid >> 2, sk = (tid & 3) * 8;
    const int fr = lane & 15, ks = (lane >> 4) * 8;

    if (EPI == 0) {
        if (blockIdx.x == 0 && blockIdx.y == 0) {
            if (rs) {
                const float4 zf = {0.f, 0.f, 0.f, 0.f};
                #pragma unroll
                for (int b = 0; b < 3; ++b)
                    *(float4*)&rs[b * KN + tid * 4] = zf;
            }
            if (dout && tid == 0) *dout = 0.f;
        }
    }

    f32x4 acc[2][2];
    #pragma unroll
    for (int i = 0; i < 2; i++)
        #pragma unroll
        for (int j = 0; j < 2; j++) acc[i][j] = (f32x4)0.f;

    for (int k0 = 0; k0 < N_; k0 += 128) {
        __syncthreads();
        #pragma unroll
        for (int sg = 0; sg < 4; ++sg) {
            __builtin_amdgcn_global_load_lds(
                (const __attribute__((address_space(1))) unsigned int*)
                    (A + (size_t)(bm + sr) * N_ + k0 + sg * 32 + sk),
                (__attribute__((address_space(3))) unsigned int*)&As[sg][sr * 32 + sk],
                16, 0, 0);
            __builtin_amdgcn_global_load_lds(
                (const __attribute__((address_space(1))) unsigned int*)
                    (B + (size_t)(bn + sr) * N_ + k0 + sg * 32 + sk),
                (__attribute__((address_space(3))) unsigned int*)&Bs[sg][sr * 32 + sk],
                16, 0, 0);
        }
        __syncthreads();
        #pragma unroll
        for (int sg = 0; sg < 4; ++sg) {
            short8 af[2], bf[2];
            #pragma unroll
            for (int mi = 0; mi < 2; ++mi)
                af[mi] = *(const short8*)&As[sg][(wr * 32 + mi * 16 + fr) * 32 + ks];
            #pragma unroll
            for (int ni = 0; ni < 2; ++ni)
                bf[ni] = *(const short8*)&Bs[sg][(wc * 32 + ni * 16 + fr) * 32 + ks];
            #pragma unroll
            for (int mi = 0; mi < 2; ++mi)
                #pragma unroll
                for (int ni = 0; ni < 2; ++ni)
                    acc[mi][ni] = __builtin_amdgcn_mfma_f32_16x16x32_bf16(
                        af[mi], bf[ni], acc[mi][ni], 0, 0, 0);
        }
    }

    const int r0 = bm + wr * 32, c0 = bn + wc * 32;
    const int rq = (lane >> 4) * 4;

    if (EPI == 0) {
        bfu* C = (bfu*)Cp;
        #pragma unroll
        for (int mi = 0; mi < 2; ++mi)
            #pragma unroll
            for (int ni = 0; ni < 2; ++ni)
                #pragma unroll
                for (int q = 0; q < 4; ++q)
                    C[(size_t)(r0 + mi * 16 + rq + q) * N_ + c0 + ni * 16 + fr]
                        = f2b(acc[mi][ni][q]);
    } else if (EPI == 2) {
        bfu* C = (bfu*)Cp;
        float rsum[2][4];
        #pragma unroll
        for (int mi = 0; mi < 2; ++mi)
            #pragma unroll
            for (int q = 0; q < 4; ++q) rsum[mi][q] = 0.f;
        #pragma unroll
        for (int mi = 0; mi < 2; ++mi)
            #pragma unroll
            for (int ni = 0; ni < 2; ++ni)
                #pragma unroll
                for (int q = 0; q < 4; ++q) {
                    const int row = r0 + mi * 16 + rq + q;
                    const int col = c0 + ni * 16 + fr;
                    const float cost = rv[col] + cv[row] - 2.f * acc[mi][ni][q];
                    const float t = b2f(C[(size_t)row * N_ + col]);
                    const bfu tn = f2b(expf(-cost * INVB) * t);
                    C[(size_t)row * N_ + col] = tn;
                    rsum[mi][q] += b2f(tn);
                }
        #pragma unroll
        for (int mi = 0; mi < 2; ++mi)
            #pragma unroll
            for (int q = 0; q < 4; ++q) {
                float v = rsum[mi][q];
                v += __shfl_xor(v, 1);
                v += __shfl_xor(v, 2);
                v += __shfl_xor(v, 4);
                v += __shfl_xor(v, 8);
                if (fr == 0)
                    atomicAdd(&rs[r0 + mi * 16 + rq + q], v);
            }
    } else {  // EPI == 3: distance reduce
        const bfu* C = (const bfu*)Cp;
        float bs = 0.f;
        #pragma unroll
        for (int mi = 0; mi < 2; ++mi)
            #pragma unroll
            for (int ni = 0; ni < 2; ++ni)
                #pragma unroll
                for (int q = 0; q < 4; ++q) {
                    const int row = r0 + mi * 16 + rq + q;
                    const int col = c0 + ni * 16 + fr;
                    bs += (rv[col] + cv[row] - 2.f * acc[mi][ni][q]) *
                          b2f(C[(size_t)row * N_ + col]);
                }
        #pragma unroll
        for (int off = 32; off; off >>= 1) bs += __shfl_down(bs, off);
        __shared__ float wred[4];
        if (lane == 0) wred[wv] = bs;
        __syncthreads();
        if (tid == 0) atomicAdd(dout, wred[0] + wred[1] + wred[2] + wred[3]);
    }
}

/* ============ rank-1 first OT step (it=0): prox + first b + rs zeroing ==== */
__global__ __launch_bounds__(256)
void prox1_k(bfu* __restrict__ Tt, const float* __restrict__ c2,
             const float* __restrict__ u, const float* __restrict__ d2,
             const float* __restrict__ w, const float* __restrict__ ps,
             const float* __restrict__ pb, float* __restrict__ bv,
             float* __restrict__ rs1, int zs, int nb) {
    const int b = blockIdx.x;
    const int z  = (nb == 8) ? (b & 7) : 0;      // XCD-affine
    const int rp = (nb == 8) ? (b >> 3) : b;
    const int tid = threadIdx.x;

    if (rp < 2) {   // zero rs1 (rp==0) / rs2 (rp==1) for slice z
        const float4 zf = {0.f, 0.f, 0.f, 0.f};
        *(float4*)&rs1[rp * KN + z * N_ + tid * 4] = zf;
    }

    const int half = tid >> 7;
    const int j = rp * 2 + half;
    const int i0 = (tid & 127) * 8;
    const float d2j = d2[j], wj = w[j], pbj = pb[j];
    const float* c2z = c2 + z * zs + i0;
    const float* uz  = u  + z * zs + i0;
    const float* psz = ps + z * zs + i0;
    bfu o[8];
    float s = 0.f;
    #pragma unroll
    for (int t = 0; t < 8; ++t) {
        const float cost = c2z[t] + d2j - 2.f * uz[t] * wj;
        o[t] = f2b(expf(-cost * INVB) * psz[t] * pbj);
        s += b2f(o[t]);
    }
    *(short8*)&Tt[((size_t)z << 20) + ((size_t)j << 10) + i0] = *(short8*)o;
    #pragma unroll
    for (int off = 32; off; off >>= 1) s += __shfl_down(s, off);
    __shared__ float red[4];
    if ((tid & 63) == 0) red[tid >> 6] = s;
    __syncthreads();
    if ((tid & 127) == 0)
        bv[z * N_ + j] = pbj / ((red[half * 2] + red[half * 2 + 1]) * INVN + EPSV);
}

/* ============ merged reduce8 + prox (row-per-block, 2 rows each) ============ */
template<int NB>
__global__ __launch_bounds__(256)
void redprox_k(const bfu* __restrict__ part, bfu* __restrict__ Gbt,
               float* __restrict__ d2out, float* __restrict__ wout,
               float* __restrict__ out1,
               const float* __restrict__ c2, const float* __restrict__ u,
               bfu* __restrict__ Tt, float* __restrict__ bv,
               float* __restrict__ rs12) {
    const int tid = threadIdx.x;
    if (blockIdx.x < 16) {   // zero rs1|rs2 (2*KN floats across 16 blocks)
        const float4 zf = {0.f, 0.f, 0.f, 0.f};
        *(float4*)&rs12[blockIdx.x * 1024 + tid * 4] = zf;
    }
    __shared__ float red[8];
    __shared__ float bc[2];
    #pragma unroll
    for (int rep = 0; rep < 2; ++rep) {
        const int row = blockIdx.x + rep * 512;
        const size_t idx = (size_t)row * N_ + tid * 4;
        float4 s = {0.f, 0.f, 0.f, 0.f};
        #pragma unroll
        for (int sl = 0; sl < K_; ++sl) {
            bfu p[4];
            *(ulong1*)p = *(const ulong1*)&part[(size_t)sl * NN + idx];
            s.x += b2f(p[0]); s.y += b2f(p[1]);
            s.z += b2f(p[2]); s.w += b2f(p[3]);
        }
        const float sc = 1048576.f;   // N^2 (pm uniform)
        s.x *= sc; s.y *= sc; s.z *= sc; s.w *= sc;
        bfu o[4];
        o[0] = f2b(s.x); o[1] = f2b(s.y); o[2] = f2b(s.z); o[3] = f2b(s.w);
        *(ulong1*)&Gbt[idx] = *(ulong1*)o;
        if (out1) {   // out+1 is only 4B-aligned: scalar stores
            out1[idx + 0] = s.x; out1[idx + 1] = s.y;
            out1[idx + 2] = s.z; out1[idx + 3] = s.w;
        }
        float r2 = s.x * s.x + s.y * s.y + s.z * s.z + s.w * s.w;
        float r1 = s.x + s.y + s.z + s.w;
        #pragma unroll
        for (int off = 32; off; off >>= 1) {
            r2 += __shfl_down(r2, off);
            r1 += __shfl_down(r1, off);
        }
        if ((tid & 63) == 0) {
            red[(tid >> 6) * 2]     = r2;
            red[(tid >> 6) * 2 + 1] = r1;
        }
        __syncthreads();
        if (tid == 0) {
            const float d2j = (red[0] + red[2] + red[4] + red[6]) * INVN;
            const float wj  = (red[1] + red[3] + red[5] + red[7]) * INVN;
            d2out[row] = d2j; wout[row] = wj;
            bc[0] = d2j; bc[1] = wj;
        }
        __syncthreads();
        const float d2j = bc[0], wj = bc[1];
        const float sc2 = INVN * INVN;   // ps * pb (both uniform)
        #pragma unroll
        for (int z = 0; z < NB; ++z) {
            const float4 cv4 = *(const float4*)(c2 + z * N_ + tid * 4);
            const float4 uv4 = *(const float4*)(u  + z * N_ + tid * 4);
            bfu t[4];
            t[0] = f2b(expf(-(cv4.x + d2j - 2.f * uv4.x * wj) * INVB) * sc2);
            t[1] = f2b(expf(-(cv4.y + d2j - 2.f * uv4.y * wj) * INVB) * sc2);
            t[2] = f2b(expf(-(cv4.z + d2j - 2.f * uv4.z * wj) * INVB) * sc2);
            t[3] = f2b(expf(-(cv4.w + d2j - 2.f * uv4.w * wj) * INVB) * sc2);
            *(ulong1*)&Tt[(size_t)z * NN + idx] = *(ulong1*)t;
            float rsum = b2f(t[0]) + b2f(t[1]) + b2f(t[2]) + b2f(t[3]);
            #pragma unroll
            for (int off = 32; off; off >>= 1) rsum += __shfl_down(rsum, off);
            if ((tid & 63) == 0) red[tid >> 6] = rsum;
            __syncthreads();
            if (tid == 0)
                bv[z * N_ + row] = INVN /
                    ((red[0] + red[1] + red[2] + red[3]) * INVN + EPSV);
            __syncthreads();
        }
    }
}

/* ============ Sinkhorn column pass (z -> XCD affine) ============
   prologue: b[j] from BSRC (0: bvin | 1: raw row-sums*INVN | 2: weighted rsin)
   column reduce (low VGPR): a[i] = ps[i]/(sum_j T[j][i]*b[j]+eps)
   epilogue TUPD=0: stash a[] in LDS, re-partition one-thread-per-row,
                    coalesced row segment dot -> 1 atomicAdd/row
            TUPD=1: rescale own column stripe T[j][i] *= a[i]*b[j] (L2-hot). */
template<int NB, int BSRC, int TUPD>
__global__ __launch_bounds__(1024)
void sinka_k(bfu* __restrict__ Tt, const float* __restrict__ bvin,
             const float* __restrict__ rsin, const float* __restrict__ ps,
             int pstr, float* __restrict__ rsnext) {
    constexpr int CPB = (NB == 8) ? 32 : 8;
    constexpr int RG  = 1024 / CPB;          // 32 or 128
    constexpr int RPG = N_ / RG;             // 32 or 8
    int z, cb;
    if (NB == 8) { z = blockIdx.x & 7; cb = blockIdx.x >> 3; }   // 256 blocks
    else         { z = 0;              cb = blockIdx.x; }        // 128 blocks
    const int tid = threadIdx.x;
    const int cl = tid % CPB, rg = tid / CPB;
    const int i = cb * CPB + cl;
    const int zN = z * N_;
    bfu* Tz = Tt + (size_t)z * NN;

    __shared__ float bvs[1024];
    __shared__ float red[1024];
    __shared__ float avs[CPB];
    if (BSRC == 0)      bvs[tid] = bvin[zN + tid];
    else if (BSRC == 1) bvs[tid] = INVN / (rsin[zN + tid] * INVN + EPSV);
    else                bvs[tid] = INVN / (rsin[zN + tid] + EPSV);
    __syncthreads();

    float s = 0.f;
    const int j0 = rg * RPG;
    #pragma unroll 8
    for (int j = j0; j < j0 + RPG; ++j)
        s += b2f(Tz[(size_t)j * N_ + i]) * bvs[j];
    red[tid] = s;
    __syncthreads();
    #pragma unroll
    for (int h = RG / 2; h > 0; h >>= 1) {
        if (rg < h) red[rg * CPB + cl] += red[(rg + h) * CPB + cl];
        __syncthreads();
    }
    const float avi = ps[z * pstr + i] / (red[cl] + EPSV);

    if (TUPD) {
        // fused tupd: rescale own column stripe (L2-hot re-read)
        for (int j = j0; j < j0 + RPG; ++j) {
            const size_t o = (size_t)j * N_ + i;
            Tz[o] = f2b(b2f(Tz[o]) * avi * bvs[j]);
        }
    } else {
        // emit next-iteration row sums: rs'[j] += sum_{i in block} T[j][i]*a[i]
        if (rg == 0) avs[cl] = avi;
        __syncthreads();
        const bfu* Tr = Tz + (size_t)tid * N_ + cb * CPB;   // row = tid
        float v = 0.f;
        #pragma unroll
        for (int q8 = 0; q8 < CPB; q8 += 8) {
            bfu t[8];
            *(short8*)t = *(const short8*)&Tr[q8];
            #pragma unroll
            for (int q = 0; q < 8; ++q) v += b2f(t[q]) * avs[q8 + q];
        }
        atomicAdd(&rsnext[zN + tid], v);
    }
}

/* ============ merged prep: atoms (z<8, sigmoid) + Gm (z==8) ============ */
__global__ void prep_k(const float* __restrict__ atoms, const float* __restrict__ Gm,
                       bfu* __restrict__ Gkt, bfu* __restrict__ Gmt,
                       float* __restrict__ Gk2ps, float* __restrict__ Gku,
                       float* __restrict__ Gm2pm, float* __restrict__ Gmu) {
    const int z = blockIdx.y;
    const int sig = (z < 8);
    const float* X = sig ? atoms + (size_t)z * NN : Gm;
    bfu*  Y  = sig ? Gkt + (size_t)z * NN : Gmt;
    float* y2 = sig ? Gk2ps + z * N_ : Gm2pm;
    float* y1 = sig ? Gku + z * N_ : Gmu;
    const int wv = threadIdx.x >> 6, lane = threadIdx.x & 63;
    const int r = blockIdx.x * 4 + wv;
    const float* Xr = X + (size_t)r * N_;
    bfu* Yr = Y + (size_t)r * N_;
    float s2 = 0.f, s1 = 0.f;
    for (int c = lane * 4; c < N_; c += 256) {
        float4 v = *(const float4*)(Xr + c);
        if (sig) {
            v.x = 1.f / (1.f + expf(-v.x));
            v.y = 1.f / (1.f + expf(-v.y));
            v.z = 1.f / (1.f + expf(-v.z));
            v.w = 1.f / (1.f + expf(-v.w));
        }
        bfu o[4];
        o[0] = f2b(v.x); o[1] = f2b(v.y); o[2] = f2b(v.z); o[3] = f2b(v.w);
        *(ulong1*)&Yr[c] = *(ulong1*)o;
        s2 += v.x * v.x + v.y * v.y + v.z * v.z + v.w * v.w;
        s1 += v.x + v.y + v.z + v.w;
    }
    #pragma unroll
    for (int off = 32; off; off >>= 1) {
        s2 += __shfl_down(s2, off);
        s1 += __shfl_down(s1, off);
    }
    if (lane == 0) {
        y2[r] = s2 * INVN;
        y1[r] = s1 * INVN;
    }
}

/* ============ host sequence ============ */

// Full Sinkhorn (3 iterations) in 3 dispatches.
template<int NB, int BSRC1>
static inline void sink_tail(bfu* Tt, const float* ps, int pstr,
                             float* bvec, float* rs, hipStream_t stream) {
    const dim3 ga((NB == 8) ? 256 : 128);
    float* rs1 = rs + KN;
    float* rs2 = rs + 2 * KN;
    sinka_k<NB, BSRC1, 0><<<ga, dim3(1024), 0, stream>>>(Tt, bvec, rs, ps, pstr, rs1);
    sinka_k<NB, 2, 0><<<ga, dim3(1024), 0, stream>>>(Tt, nullptr, rs1, ps, pstr, rs2);
    sinka_k<NB, 2, 1><<<ga, dim3(1024), 0, stream>>>(Tt, nullptr, rs2, ps, pstr, nullptr);
}

extern "C" void kernel_launch(void* const* d_in, const int* in_sizes, int n_in,
                              void* d_out, int out_size, void* d_ws, size_t ws_size,
                              hipStream_t stream) {
    const float* Gm    = (const float*)d_in[0];
    const float* pm    = (const float*)d_in[1];
    const float* atoms = (const float*)d_in[2];
    const float* probs = (const float*)d_in[3];
    const float* wts   = (const float*)d_in[4];
    float* out = (float*)d_out;                  // [0]=d_fgw, [1..]=G_bary (fp32)

    char* base = (char*)d_ws;
    bfu*   Gkt  = (bfu*)base;                    base += K_ * NN * 2;
    bfu*   Tt   = (bfu*)base;                    base += K_ * NN * 2;
    bfu*   M    = (bfu*)base;                    base += K_ * NN * 2;
    bfu*   part = (bfu*)base;                    base += K_ * NN * 2;
    bfu*   Gbt  = (bfu*)base;                    base += NN * 2;
    bfu*   Gmt  = (bfu*)base;                    base += NN * 2;
    float* Gk2ps = (float*)base;                 base += KN * 4;
    float* Gku   = (float*)base;                 base += KN * 4;
    float* Gm2pm = (float*)base;                 base += N_ * 4;
    float* Gmu   = (float*)base;                 base += N_ * 4;
    float* Gb2pb = (float*)base;                 base += N_ * 4;
    float* Gbw   = (float*)base;                 base += N_ * 4;
    float* bvec  = (float*)base;                 base += KN * 4;
    float* rs    = (float*)base;                 base += 3 * KN * 4;  // rs|rs1|rs2

    const dim3 blk(256);
    const dim3 g8(8, 8, 8);      // (z, m-tile, n-tile): z -> XCD
    const dim3 g64(16, 16);      // 64^2 tiles: n-tile -> XCD

    // merged setup: atoms sigmoid cast + moments (z<8), Gm cast + moments (z=8)
    prep_k<<<dim3(256, 9), blk, 0, stream>>>(atoms, Gm, Gkt, Gmt,
                                             Gk2ps, Gku, Gm2pm, Gmu);

    for (int it = 0; it < GWBL; ++it) {
        // iteration 0: barycenter == Gm; iteration 1: Gb written by redprox
        const bfu*   GbtU = it ? Gbt : Gmt;
        const float* d2U  = it ? Gb2pb : Gm2pm;

        if (it == 0)   // rank-1 prox vs Gm (+ first-b + rs1/rs2 zeroing)
            prox1_k<<<512 * K_, blk, 0, stream>>>(Tt, Gk2ps, Gku, Gm2pm, Gmu,
                                                  probs, pm, bvec, rs + KN, N_, K_);
        // else: redprox_k<8> at end of previous iter already wrote Tt/bvec/rs
        sink_tail<K_, 0>(Tt, probs, N_, bvec, rs, stream);
        for (int ot = 1; ot < OTL; ++ot) {
            // M[i][n] = sum_k Gk[i][k]*Tt[n][k]  (= Gs @ T); zero rs buffers
            bgemm_k<0><<<g8, blk, 0, stream>>>(Gkt, Tt, M, NN, NN, NN,
                nullptr, nullptr, nullptr, rs);
            // prox in place + row-sum atomics -> rs
            bgemm_k<2><<<g8, blk, 0, stream>>>(GbtU, M, Tt, 0, NN, NN,
                Gk2ps, d2U, nullptr, rs);
            sink_tail<K_, 1>(Tt, probs, N_, bvec, rs, stream);
        }
        // GTt[j][i'] = sum_k Tt[j][k]*Gk[i'][k]   (= (Gk @ T)^T)
        bgemm_k<0><<<g8, blk, 0, stream>>>(Tt, Gkt, M, NN, NN, NN,
            nullptr, nullptr, nullptr, nullptr);
        // part[z][i][j] = bf16( w_z * sum_n Tt[z][i][n]*GTt[z][j][n] )
        bgemm_k<1><<<g8, blk, 0, stream>>>(Tt, M, part, NN, NN, NN,
            nullptr, nullptr, wts, nullptr);
        // merged: Gb combine + moments + prox for next phase + first-b + rs zero
        if (it == 0)
            redprox_k<8><<<512, blk, 0, stream>>>(part, Gbt, Gb2pb, Gbw,
                nullptr, Gk2ps, Gku, Tt, bvec, rs + KN);
        else
            redprox_k<1><<<512, blk, 0, stream>>>(part, Gbt, Gb2pb, Gbw,
                out + 1, Gm2pm, Gmu, Tt, bvec, rs + KN);
    }

    // ---- final fgwd(Gm, pm, Gb, pm) — Tt/bvec already set by redprox<1> ----
    sink_tail<1, 0>(Tt, pm, 0, bvec, rs, stream);
    for (int ot = 1; ot < OTL; ++ot) {
        gemm64_k<0><<<g64, blk, 0, stream>>>(Gmt, Tt, M,
            nullptr, nullptr, rs, nullptr);
        gemm64_k<2><<<g64, blk, 0, stream>>>(Gbt, M, Tt,
            Gm2pm, Gb2pb, rs, nullptr);
        sink_tail<1, 1>(Tt, pm, 0, bvec, rs, stream);
    }
    // d = sum_ij (Gm2pm[i] + Gb2pb[j] - 2*(Gm T Gb^T)[i][j]) * T[i][j]
    gemm64_k<0><<<g64, blk, 0, stream>>>(Gmt, Tt, M,
        nullptr, nullptr, nullptr, out /* zero d */);
    gemm64_k<3><<<g64, blk, 0, stream>>>(Gbt, M, Tt,
        Gm2pm, Gb2pb, nullptr, out);
}